// Round 16
// baseline (407.120 us; speedup 1.0000x reference)
//
#include <hip/hip_runtime.h>

typedef __attribute__((ext_vector_type(4))) float f32x4;
typedef __attribute__((ext_vector_type(8))) __bf16 bf16x8;

#define B_SZ   16
#define T_SZ   256
#define BT_SZ  4096      // B*T
#define N_VOX  20000
#define INDIM  800
#define K1P    896       // padded K for GEMM1 (NT=14, even)
#define K_DIM  4000
#define KP     4096      // padded K / hidden
#define R_DIM  1000
#define RP     1024      // padded rest
#define SPLITK 4

__device__ __forceinline__ unsigned short f2bf(float f) {
  unsigned int u = __builtin_bit_cast(unsigned int, f);
  u += 0x7fffu + ((u >> 16) & 1u);
  return (unsigned short)(u >> 16);
}
__device__ __forceinline__ float bf2f(unsigned short h) {
  unsigned int u = ((unsigned int)h) << 16;
  return __builtin_bit_cast(float, u);
}
__device__ __forceinline__ void gload16(const void* g, void* l) {
  __builtin_amdgcn_global_load_lds(
      (const __attribute__((address_space(1))) void*)g,
      (__attribute__((address_space(3))) void*)l, 16, 0, 0);
}

// ================= fused prep kernel =================
#define PREP_CVT    4096
#define PREP_W1     3584     // 28 x 128
#define PREP_W2     16384    // 128 x 128
#define PREP_W3     4096     // 128 x 32
#define PREP_COV    320      // 20 x 16

__device__ void dev_transpose(const float* __restrict__ W,
                              unsigned short* __restrict__ WT,
                              int K, int N, int Kpad, int Npad,
                              int kb, int nb, int tx, int ty,
                              float (*tile)[33]) {
  int k0 = kb * 32, n0 = nb * 32;
  for (int i = ty; i < 32; i += 8) {
    int k = k0 + i, n = n0 + tx;
    tile[i][tx] = (k < K && n < N) ? W[(size_t)k * N + n] : 0.f;
  }
  __syncthreads();
  for (int i = ty; i < 32; i += 8) {
    int n = n0 + i, k = k0 + tx;
    if (n < Npad && k < Kpad)
      WT[(size_t)n * Kpad + k] = f2bf(tile[tx][i]);
  }
}

__global__ __launch_bounds__(256) void prep_kernel(
    const float* __restrict__ x, unsigned short* __restrict__ xb,
    const float* __restrict__ W1, unsigned short* __restrict__ w1t,
    const float* __restrict__ W2, unsigned short* __restrict__ w2t,
    const float* __restrict__ W3, unsigned short* __restrict__ w3t,
    const int* __restrict__ bmask, unsigned char* __restrict__ cov) {
  __shared__ float tile[32][33];
  int id = blockIdx.x;
  const int tid = threadIdx.x;
  const int tx = tid & 31, ty = tid >> 5;

  if (id < PREP_CVT) {                       // x -> xb [4096][896] bf16
    int row = id, c4 = tid;
    if (c4 < K1P / 4) {
      ushort4 o = {0, 0, 0, 0};
      if (c4 < INDIM / 4) {
        float4 v = ((const float4*)(x + (size_t)row * INDIM))[c4];
        o.x = f2bf(v.x); o.y = f2bf(v.y); o.z = f2bf(v.z); o.w = f2bf(v.w);
      }
      ((ushort4*)(xb + (size_t)row * K1P))[c4] = o;
    }
    return;
  }
  id -= PREP_CVT;
  if (id < PREP_W1) {                        // W1 [800,4000] -> [4096,896]
    dev_transpose(W1, w1t, INDIM, K_DIM, K1P, KP, id % 28, id / 28, tx, ty, tile);
    return;
  }
  id -= PREP_W1;
  if (id < PREP_W2) {                        // W2 [4000,4000] -> [4096,4096]
    dev_transpose(W2, w2t, K_DIM, K_DIM, KP, KP, id % 128, id / 128, tx, ty, tile);
    return;
  }
  id -= PREP_W2;
  if (id < PREP_W3) {                        // W3 [4000,1000] -> [1024,4096]
    dev_transpose(W3, w3t, K_DIM, R_DIM, KP, RP, id % 128, id / 128, tx, ty, tile);
    return;
  }
  id -= PREP_W3;
  {                                          // covered: id = n4b + 20*b
    int n4 = (id % 20) * 256 + tid;
    int b = id / 20;
    if (n4 >= N_VOX / 4) return;
    const int4* p = (const int4*)(bmask + (size_t)b * T_SZ * N_VOX) + n4;
    int4 a = {0, 0, 0, 0};
    for (int t0 = 0; t0 < T_SZ; t0 += 8) {
      int4 c[8];
#pragma unroll
      for (int tt = 0; tt < 8; ++tt)
        c[tt] = p[(size_t)(t0 + tt) * (N_VOX / 4)];
#pragma unroll
      for (int tt = 0; tt < 8; ++tt) {
        a.x |= c[tt].x; a.y |= c[tt].y; a.z |= c[tt].z; a.w |= c[tt].w;
      }
      if (a.x && a.y && a.z && a.w) break;
    }
    uchar4 o;
    o.x = (unsigned char)(a.x != 0); o.y = (unsigned char)(a.y != 0);
    o.z = (unsigned char)(a.z != 0); o.w = (unsigned char)(a.w != 0);
    *(uchar4*)(cov + (size_t)b * N_VOX + (size_t)n4 * 4) = o;
  }
}

// ---------- map (512-thread device fn): srcmap[n] = j / K_DIM+rank / -1 ----------
__device__ void dev_map(const int* __restrict__ index,
                        const unsigned char* __restrict__ cov,
                        int* __restrict__ srcmap, int b, char* smembase) {
  const int tid = threadIdx.x;
  int* wsum = (int*)smembase;                 // 8 ints
  int* s_running = (int*)(smembase + 64);
  int* sm = srcmap + (size_t)b * N_VOX;
  for (int n = tid; n < N_VOX; n += 512) sm[n] = -1;
  __syncthreads();
  const int* idx = index + (size_t)b * K_DIM;
  for (int j = tid; j < K_DIM; j += 512) sm[idx[j]] = j;
  __syncthreads();
  if (tid == 0) *s_running = 0;
  __syncthreads();
  const int lane = tid & 63, wid = tid >> 6;  // 8 waves
  const unsigned char* cv = cov + (size_t)b * N_VOX;
  for (int base = 0; base < N_VOX; base += 512) {
    int n = base + tid;
    bool flag = (n < N_VOX) && (!cv[n]) && (sm[n] < 0);
    unsigned long long bal = __ballot(flag);
    if (lane == 0) wsum[wid] = __popcll(bal);
    __syncthreads();
    int woff = 0, tot = 0;
    for (int w = 0; w < 8; ++w) {
      int c = wsum[w];
      if (w < wid) woff += c;
      tot += c;
    }
    int rank = *s_running + woff + __popcll(bal & ((1ull << lane) - 1ull));
    if (flag && rank < R_DIM) sm[n] = K_DIM + rank;
    __syncthreads();
    if (tid == 0) *s_running += tot;
    __syncthreads();
  }
}

// ---------- GEMM 256x256 body, K-split-half LDS, 2 barriers/tile ----------
// r16: sync only at end of phases 2 and 4 (was every phase). Ledger (per
// wave, stage order A0,B0,A1,B1, 2 loads each, FIFO):
//   end-p4: outstanding 8 -> vmcnt(4) retires A0',B0' (read next p1/p2);
//   end-p2: outstanding 8 -> vmcnt(4) retires A1',B1' (read p3/p4).
// Phases 1,2 read only kh0; 3,4 only kh1 -> mid-tile barrier@p2 + boundary
// barrier@p4 give full cross-wave visibility. 32 MFMA per barrier-interval.
// vmcnt placed AFTER the MFMA cluster (extra flight time). Never drains.
template <bool SPLIT>
__device__ __forceinline__ void gemm256_body(
    const unsigned short* __restrict__ A,
    const unsigned short* __restrict__ BTm,
    const float* __restrict__ bias, int nbias,
    unsigned short* __restrict__ C,
    int K, int lda, int ldb, int ldc, size_t zstride,
    int bm, int bn, int kz, char* smem) {
  const int tid = threadIdx.x;
  const int wid = tid >> 6, lane = tid & 63;
  const int wm = wid >> 2, wn = wid & 3;
  const int r15 = lane & 15, kg = lane >> 4;
  if constexpr (SPLIT) {
    A += (size_t)kz * K;
    BTm += (size_t)kz * K;
    C += (size_t)kz * zstride;
  }

  // staging: thread covers 16B; source col16 slot pre-swizzled by (row>>1)&3
  const int srow = tid >> 2;
  const int scol = (((tid & 3) ^ ((srow >> 1) & 3)) * 8);  // ushort offset
  const unsigned short* gA = A + (size_t)(bm * 256 + srow) * lda + scol;
  const unsigned short* gB = BTm + (size_t)(bn * 256 + srow) * ldb + scol;

  // ds_read byte offsets: same involution on the read side
  const int cxor = ((kg ^ ((r15 >> 1) & 3)) * 16);
  const int aoff = (wm * 128 + r15) * 64 + cxor;   // + mh*4096 + i*1024
  const int boff = (wn * 64 + r15) * 64 + cxor;    // + j*1024

  f32x4 acc[8][4] = {};
  bf16x8 bfr[4];

#define STAGE_HALF(S, MAT, KH, TN)                                            \
  {                                                                           \
    const unsigned short* g =                                                 \
        ((MAT) ? gB : gA) + (size_t)(TN) * 64 + (KH) * 32;                    \
    char* l = smem + (S) * 65536 + (MAT) * 32768 + (KH) * 16384 + tid * 16;   \
    gload16(g, l);                                                            \
    gload16(g + (size_t)128 * ((MAT) ? ldb : lda), l + 8192);                 \
  }

#define PHASE(S, KS, MH, TN, DOSYNC)                                          \
  {                                                                           \
    bf16x8 af[4];                                                             \
    if ((MH) == 0) {                                                          \
      _Pragma("unroll")                                                       \
      for (int j = 0; j < 4; ++j)                                             \
        bfr[j] = *(const bf16x8*)(smem + (S) * 65536 + 32768 +                \
                                  (KS) * 16384 + boff + j * 1024);            \
    }                                                                         \
    _Pragma("unroll")                                                         \
    for (int i = 0; i < 4; ++i)                                               \
      af[i] = *(const bf16x8*)(smem + (S) * 65536 + (KS) * 16384 +            \
                               (MH) * 4096 + aoff + i * 1024);                \
    STAGE_HALF((S) ^ 1, (MH), (KS), TN)                                       \
    __builtin_amdgcn_s_setprio(1);                                            \
    _Pragma("unroll")                                                         \
    for (int i = 0; i < 4; ++i)                                               \
      _Pragma("unroll")                                                       \
      for (int j = 0; j < 4; ++j)                                             \
        acc[(MH) * 4 + i][j] = __builtin_amdgcn_mfma_f32_16x16x32_bf16(       \
            af[i], bfr[j], acc[(MH) * 4 + i][j], 0, 0, 0);                    \
    __builtin_amdgcn_s_setprio(0);                                            \
    if (DOSYNC) {                                                             \
      asm volatile("s_waitcnt vmcnt(4)" ::: "memory");                        \
      asm volatile("s_barrier" ::: "memory");                                 \
    }                                                                         \
  }

#define TILE4(S, TN)                                                          \
  PHASE(S, 0, 0, TN, 0)                                                       \
  PHASE(S, 0, 1, TN, 1)                                                       \
  PHASE(S, 1, 0, TN, 0)                                                       \
  PHASE(S, 1, 1, TN, 1)

  const int NT = K >> 6;   // K/64, must be even
  // prologue: stage tile 0 fully into buf0 (A0,B0,A1,B1); retire A0,B0.
  STAGE_HALF(0, 0, 0, 0)
  STAGE_HALF(0, 1, 0, 0)
  STAGE_HALF(0, 0, 1, 0)
  STAGE_HALF(0, 1, 1, 0)
  asm volatile("s_waitcnt vmcnt(4)" ::: "memory");
  asm volatile("s_barrier" ::: "memory");

  for (int tp = 0; tp < NT; tp += 2) {
    const int tn1 = tp + 1;                          // always < NT (NT even)
    TILE4(0, tn1)
    const int tn2 = (tp + 2 < NT) ? tp + 2 : NT - 1; // clamp: harmless restage
    TILE4(1, tn2)
  }

#undef STAGE_HALF
#undef PHASE
#undef TILE4

#pragma unroll
  for (int f = 0; f < 8; ++f) {
    const int row0 = bm * 256 + wm * 128 + f * 16 + kg * 4;
#pragma unroll
    for (int j = 0; j < 4; ++j) {
      const int col = bn * 256 + wn * 64 + j * 16 + r15;
      float bv = 0.f;
      if constexpr (!SPLIT) bv = bias[(col < nbias) ? col : (nbias - 1)];
#pragma unroll
      for (int r = 0; r < 4; ++r)
        C[(size_t)(row0 + r) * ldc + col] = f2bf(acc[f][j][r] + bv);
    }
  }
}

template <bool SPLIT>
__global__ __launch_bounds__(512, 1) void gemm256(
    const unsigned short* __restrict__ A,
    const unsigned short* __restrict__ BTm,
    const float* __restrict__ bias, int nbias,
    unsigned short* __restrict__ C,
    int K, int lda, int ldb, int ldc, size_t zstride) {
  __shared__ __align__(16) char smem[131072];
  gemm256_body<SPLIT>(A, BTm, bias, nbias, C, K, lda, ldb, ldc, zstride,
                      blockIdx.y, blockIdx.x, SPLIT ? blockIdx.z : 0, smem);
}

// GEMM1 fused with map: blocks [0,256) = 16x16 gemm tiles; [256,272) = map(b).
// map runs in GEMM1's shadow on otherwise-idle CUs (independent data).
__global__ __launch_bounds__(512, 1) void gemm1_map(
    const unsigned short* __restrict__ A,
    const unsigned short* __restrict__ BTm,
    const float* __restrict__ bias, int nbias,
    unsigned short* __restrict__ C,
    int K, int lda, int ldb, int ldc,
    const int* __restrict__ index,
    const unsigned char* __restrict__ cov,
    int* __restrict__ srcmap) {
  __shared__ __align__(16) char smem[131072];
  const int id = blockIdx.x;
  if (id >= 256) {
    dev_map(index, cov, srcmap, id - 256, smem);
    return;
  }
  gemm256_body<false>(A, BTm, bias, nbias, C, K, lda, ldb, ldc, 0,
                      id >> 4, id & 15, 0, smem);
}

// ---------- final output assembly; split-K reduce folded in ----------
// Exact r10 form (measured best). One t per block, high TLP; srcmap re-read
// is L2-resident; NT stores (327MB never re-read).
__global__ void fill_out(const int* __restrict__ srcmap,
                         const unsigned short* __restrict__ h2b,
                         const unsigned short* __restrict__ xpart,
                         const float* __restrict__ b3,
                         float* __restrict__ out) {
  int n4 = blockIdx.x * 256 + threadIdx.x;
  if (n4 >= N_VOX / 4) return;
  int t = blockIdx.y, b = blockIdx.z;
  size_t bt = (size_t)b * T_SZ + t;
  const int4 sm = ((const int4*)(srcmap + (size_t)b * N_VOX))[n4];
  const unsigned short* hrow = h2b + bt * KP;
  const unsigned short* xrow = xpart + bt * RP;
  const size_t zs = (size_t)BT_SZ * RP;
  auto val = [&](int s) -> float {
    if (s < 0) return 0.f;
    if (s < K_DIM) return bf2f(hrow[s]);
    int r = s - K_DIM;
    float acc = b3[r];
#pragma unroll
    for (int z = 0; z < SPLITK; ++z) acc += bf2f(xrow[z * zs + r]);
    return acc;
  };
  f32x4 v;
  v.x = val(sm.x); v.y = val(sm.y); v.z = val(sm.z); v.w = val(sm.w);
  __builtin_nontemporal_store(v, (f32x4*)(out + bt * N_VOX) + n4);
}

extern "C" void kernel_launch(void* const* d_in, const int* in_sizes, int n_in,
                              void* d_out, int out_size, void* d_ws, size_t ws_size,
                              hipStream_t stream) {
  const float* x          = (const float*)d_in[0];
  const int* bm           = (const int*)d_in[1];   // bool -> int32 per harness contract
  const int* index        = (const int*)d_in[2];
  const float* W1         = (const float*)d_in[3];
  const float* b1         = (const float*)d_in[4];
  const float* W2         = (const float*)d_in[5];
  const float* b2         = (const float*)d_in[6];
  const float* W3         = (const float*)d_in[7];
  const float* b3         = (const float*)d_in[8];
  float* out = (float*)d_out;

  char* ws = (char*)d_ws;
  size_t off = 0;
  auto alloc = [&](size_t bytes) -> void* {
    void* p = ws + off;
    off += (bytes + 255) & ~(size_t)255;
    return p;
  };
  unsigned short* xb    = (unsigned short*)alloc((size_t)BT_SZ * K1P * 2);
  unsigned short* w1t   = (unsigned short*)alloc((size_t)KP * K1P * 2);
  unsigned short* w2t   = (unsigned short*)alloc((size_t)KP * KP * 2);
  unsigned short* w3t   = (unsigned short*)alloc((size_t)RP * KP * 2);
  unsigned short* h1b   = (unsigned short*)alloc((size_t)BT_SZ * KP * 2);
  unsigned short* h2b   = (unsigned short*)alloc((size_t)BT_SZ * KP * 2);
  unsigned short* xpart = (unsigned short*)alloc((size_t)SPLITK * BT_SZ * RP * 2);
  unsigned char* cov = (unsigned char*)alloc((size_t)B_SZ * N_VOX);
  int* srcmap = (int*)alloc((size_t)B_SZ * N_VOX * 4);

  // fused prep: x-cvt, 3 weight transposes, coverage
  {
    int nblk = PREP_CVT + PREP_W1 + PREP_W2 + PREP_W3 + PREP_COV;
    prep_kernel<<<nblk, 256, 0, stream>>>(x, xb, W1, w1t, W2, w2t, W3, w3t, bm, cov);
  }

  // GEMM1 (K padded to 896) + map fused
  gemm1_map<<<272, 512, 0, stream>>>(xb, w1t, b1, K_DIM, h1b,
                                     K1P, K1P, K1P, KP, index, cov, srcmap);
  {
    dim3 g(KP / 256, BT_SZ / 256);   // GEMM2
    gemm256<false><<<g, 512, 0, stream>>>(h1b, w2t, b2, K_DIM, h2b,
                                          KP, KP, KP, KP, 0);
  }
  {
    dim3 g(RP / 256, BT_SZ / 256, SPLITK);  // GEMM3: 8-phase split-K, 256 blocks
    gemm256<true><<<g, 512, 0, stream>>>(h2b, w3t, nullptr, 0, xpart,
                                         KP / SPLITK, KP, KP, RP,
                                         (size_t)BT_SZ * RP);
  }

  // output assembly (split-K reduce + bias folded in)
  {
    dim3 g((N_VOX / 4 + 255) / 256, T_SZ, B_SZ);
    fill_out<<<g, 256, 0, stream>>>(srcmap, h2b, xpart, b3, out);
  }
}

// Round 17
// 399.817 us; speedup vs baseline: 1.0183x; 1.0183x over previous
//
#include <hip/hip_runtime.h>

typedef __attribute__((ext_vector_type(4))) float f32x4;
typedef __attribute__((ext_vector_type(8))) __bf16 bf16x8;

#define B_SZ   16
#define T_SZ   256
#define BT_SZ  4096      // B*T
#define N_VOX  20000
#define INDIM  800
#define K1P    896       // padded K for GEMM1 (NT=14, even)
#define K_DIM  4000
#define KP     4096      // padded K / hidden
#define R_DIM  1000
#define RP     1024      // padded rest
#define SPLITK 4

__device__ __forceinline__ unsigned short f2bf(float f) {
  unsigned int u = __builtin_bit_cast(unsigned int, f);
  u += 0x7fffu + ((u >> 16) & 1u);
  return (unsigned short)(u >> 16);
}
__device__ __forceinline__ float bf2f(unsigned short h) {
  unsigned int u = ((unsigned int)h) << 16;
  return __builtin_bit_cast(float, u);
}
__device__ __forceinline__ void gload16(const void* g, void* l) {
  __builtin_amdgcn_global_load_lds(
      (const __attribute__((address_space(1))) void*)g,
      (__attribute__((address_space(3))) void*)l, 16, 0, 0);
}

// ================= fused prep kernel =================
#define PREP_CVT    4096
#define PREP_W1     3584     // 28 x 128
#define PREP_W2     16384    // 128 x 128
#define PREP_W3     4096     // 128 x 32
#define PREP_COV    320      // 20 x 16

__device__ void dev_transpose(const float* __restrict__ W,
                              unsigned short* __restrict__ WT,
                              int K, int N, int Kpad, int Npad,
                              int kb, int nb, int tx, int ty,
                              float (*tile)[33]) {
  int k0 = kb * 32, n0 = nb * 32;
  for (int i = ty; i < 32; i += 8) {
    int k = k0 + i, n = n0 + tx;
    tile[i][tx] = (k < K && n < N) ? W[(size_t)k * N + n] : 0.f;
  }
  __syncthreads();
  for (int i = ty; i < 32; i += 8) {
    int n = n0 + i, k = k0 + tx;
    if (n < Npad && k < Kpad)
      WT[(size_t)n * Kpad + k] = f2bf(tile[tx][i]);
  }
}

__global__ __launch_bounds__(256) void prep_kernel(
    const float* __restrict__ x, unsigned short* __restrict__ xb,
    const float* __restrict__ W1, unsigned short* __restrict__ w1t,
    const float* __restrict__ W2, unsigned short* __restrict__ w2t,
    const float* __restrict__ W3, unsigned short* __restrict__ w3t,
    const int* __restrict__ bmask, unsigned char* __restrict__ cov) {
  __shared__ float tile[32][33];
  int id = blockIdx.x;
  const int tid = threadIdx.x;
  const int tx = tid & 31, ty = tid >> 5;

  if (id < PREP_CVT) {                       // x -> xb [4096][896] bf16
    int row = id, c4 = tid;
    if (c4 < K1P / 4) {
      ushort4 o = {0, 0, 0, 0};
      if (c4 < INDIM / 4) {
        float4 v = ((const float4*)(x + (size_t)row * INDIM))[c4];
        o.x = f2bf(v.x); o.y = f2bf(v.y); o.z = f2bf(v.z); o.w = f2bf(v.w);
      }
      ((ushort4*)(xb + (size_t)row * K1P))[c4] = o;
    }
    return;
  }
  id -= PREP_CVT;
  if (id < PREP_W1) {                        // W1 [800,4000] -> [4096,896]
    dev_transpose(W1, w1t, INDIM, K_DIM, K1P, KP, id % 28, id / 28, tx, ty, tile);
    return;
  }
  id -= PREP_W1;
  if (id < PREP_W2) {                        // W2 [4000,4000] -> [4096,4096]
    dev_transpose(W2, w2t, K_DIM, K_DIM, KP, KP, id % 128, id / 128, tx, ty, tile);
    return;
  }
  id -= PREP_W2;
  if (id < PREP_W3) {                        // W3 [4000,1000] -> [1024,4096]
    dev_transpose(W3, w3t, K_DIM, R_DIM, KP, RP, id % 128, id / 128, tx, ty, tile);
    return;
  }
  id -= PREP_W3;
  {                                          // covered: id = n4b + 20*b
    int n4 = (id % 20) * 256 + tid;
    int b = id / 20;
    if (n4 >= N_VOX / 4) return;
    const int4* p = (const int4*)(bmask + (size_t)b * T_SZ * N_VOX) + n4;
    int4 a = {0, 0, 0, 0};
    for (int t0 = 0; t0 < T_SZ; t0 += 8) {
      int4 c[8];
#pragma unroll
      for (int tt = 0; tt < 8; ++tt)
        c[tt] = p[(size_t)(t0 + tt) * (N_VOX / 4)];
#pragma unroll
      for (int tt = 0; tt < 8; ++tt) {
        a.x |= c[tt].x; a.y |= c[tt].y; a.z |= c[tt].z; a.w |= c[tt].w;
      }
      if (a.x && a.y && a.z && a.w) break;
    }
    uchar4 o;
    o.x = (unsigned char)(a.x != 0); o.y = (unsigned char)(a.y != 0);
    o.z = (unsigned char)(a.z != 0); o.w = (unsigned char)(a.w != 0);
    *(uchar4*)(cov + (size_t)b * N_VOX + (size_t)n4 * 4) = o;
  }
}

// one block (1024 thr) per sample: srcmap[n] = j (index col), K_DIM+rank (rest col), -1 (zero)
__global__ void map_kernel(const int* __restrict__ index,
                           const unsigned char* __restrict__ cov,
                           int* __restrict__ srcmap) {
  int b = blockIdx.x, tid = threadIdx.x;
  int* sm = srcmap + (size_t)b * N_VOX;
  for (int n = tid; n < N_VOX; n += 1024) sm[n] = -1;
  __syncthreads();
  const int* idx = index + (size_t)b * K_DIM;
  for (int j = tid; j < K_DIM; j += 1024) sm[idx[j]] = j;
  __syncthreads();

  __shared__ int wsum[16];
  __shared__ int s_running;
  if (tid == 0) s_running = 0;
  __syncthreads();
  const int lane = tid & 63, wid = tid >> 6;
  const unsigned char* cv = cov + (size_t)b * N_VOX;
  for (int base = 0; base < N_VOX; base += 1024) {
    int n = base + tid;
    bool flag = (n < N_VOX) && (!cv[n]) && (sm[n] < 0);
    unsigned long long bal = __ballot(flag);
    if (lane == 0) wsum[wid] = __popcll(bal);
    __syncthreads();
    int woff = 0, tot = 0;
    for (int w = 0; w < 16; ++w) {
      int c = wsum[w];
      if (w < wid) woff += c;
      tot += c;
    }
    int rank = s_running + woff + __popcll(bal & ((1ull << lane) - 1ull));
    if (flag && rank < R_DIM) sm[n] = K_DIM + rank;
    __syncthreads();
    if (tid == 0) s_running += tot;
    __syncthreads();
  }
}

// ---------- GEMM 256x256, single-barrier 4-phase K-loop (r15, session best) ----------
// Phase = { ds_read frags from buf S; [vmcnt(2) at phases 2,4]; s_barrier;
// STAGE next-tile half into buf S^1; setprio(1); 16 MFMA; setprio(0) }.
// Per-wave vmcnt ledger: stage order per tile = A0,B0,A1,B1 (2 loads each,
// issued after each phase's barrier). vmcnt(2)@p2 retires prev tile's A1,B1
// (consumed p3/p4); vmcnt(2)@p4 retires this tile's A0,B0 (consumed next
// p1/p2). Prologue: 8 loads, vmcnt(4). Never drains to 0 in the loop (T4).
// NOTE: r16's 2-barrier variant regressed (+6us) — per-phase barrier
// rate-matches producer/consumer waves; keep this form.
template <bool SPLIT>
__global__ __launch_bounds__(512, 1) void gemm256(
    const unsigned short* __restrict__ A,
    const unsigned short* __restrict__ BTm,
    const float* __restrict__ bias, int nbias,
    unsigned short* __restrict__ C,
    int K, int lda, int ldb, int ldc, size_t zstride) {
  __shared__ __align__(16) char smem[131072];
  const int tid = threadIdx.x;
  const int wid = tid >> 6, lane = tid & 63;
  const int wm = wid >> 2, wn = wid & 3;
  const int r15 = lane & 15, kg = lane >> 4;
  const int bm = blockIdx.y, bn = blockIdx.x;
  if constexpr (SPLIT) {
    const int kz = blockIdx.z;
    A += (size_t)kz * K;
    BTm += (size_t)kz * K;
    C += (size_t)kz * zstride;
  }

  // staging: thread covers 16B; source col16 slot pre-swizzled by (row>>1)&3
  const int srow = tid >> 2;
  const int scol = (((tid & 3) ^ ((srow >> 1) & 3)) * 8);  // ushort offset
  const unsigned short* gA = A + (size_t)(bm * 256 + srow) * lda + scol;
  const unsigned short* gB = BTm + (size_t)(bn * 256 + srow) * ldb + scol;

  // ds_read byte offsets: same involution on the read side
  const int cxor = ((kg ^ ((r15 >> 1) & 3)) * 16);
  const int aoff = (wm * 128 + r15) * 64 + cxor;   // + mh*4096 + i*1024
  const int boff = (wn * 64 + r15) * 64 + cxor;    // + j*1024

  f32x4 acc[8][4] = {};
  bf16x8 bfr[4];

#define STAGE_HALF(S, MAT, KH, TN)                                            \
  {                                                                           \
    const unsigned short* g =                                                 \
        ((MAT) ? gB : gA) + (size_t)(TN) * 64 + (KH) * 32;                    \
    char* l = smem + (S) * 65536 + (MAT) * 32768 + (KH) * 16384 + tid * 16;   \
    gload16(g, l);                                                            \
    gload16(g + (size_t)128 * ((MAT) ? ldb : lda), l + 8192);                 \
  }

#define PHASE(S, KS, MH, TN, DOVM)                                            \
  {                                                                           \
    bf16x8 af[4];                                                             \
    if ((MH) == 0) {                                                          \
      _Pragma("unroll")                                                       \
      for (int j = 0; j < 4; ++j)                                             \
        bfr[j] = *(const bf16x8*)(smem + (S) * 65536 + 32768 +                \
                                  (KS) * 16384 + boff + j * 1024);            \
    }                                                                         \
    _Pragma("unroll")                                                         \
    for (int i = 0; i < 4; ++i)                                               \
      af[i] = *(const bf16x8*)(smem + (S) * 65536 + (KS) * 16384 +            \
                               (MH) * 4096 + aoff + i * 1024);                \
    if (DOVM) asm volatile("s_waitcnt vmcnt(2)" ::: "memory");                \
    asm volatile("s_barrier" ::: "memory");                                   \
    STAGE_HALF((S) ^ 1, (MH), (KS), TN)                                       \
    __builtin_amdgcn_s_setprio(1);                                            \
    _Pragma("unroll")                                                         \
    for (int i = 0; i < 4; ++i)                                               \
      _Pragma("unroll")                                                       \
      for (int j = 0; j < 4; ++j)                                             \
        acc[(MH) * 4 + i][j] = __builtin_amdgcn_mfma_f32_16x16x32_bf16(       \
            af[i], bfr[j], acc[(MH) * 4 + i][j], 0, 0, 0);                    \
    __builtin_amdgcn_s_setprio(0);                                            \
  }

#define TILE4(S, TN)                                                          \
  PHASE(S, 0, 0, TN, 0)                                                       \
  PHASE(S, 0, 1, TN, 1)                                                       \
  PHASE(S, 1, 0, TN, 0)                                                       \
  PHASE(S, 1, 1, TN, 1)

  const int NT = K >> 6;   // K/64, must be even
  // prologue: stage tile 0 fully into buf0 (A0,B0,A1,B1); retire A0,B0.
  STAGE_HALF(0, 0, 0, 0)
  STAGE_HALF(0, 1, 0, 0)
  STAGE_HALF(0, 0, 1, 0)
  STAGE_HALF(0, 1, 1, 0)
  asm volatile("s_waitcnt vmcnt(4)" ::: "memory");
  asm volatile("s_barrier" ::: "memory");

  for (int tp = 0; tp < NT; tp += 2) {
    const int tn1 = tp + 1;                          // always < NT (NT even)
    TILE4(0, tn1)
    const int tn2 = (tp + 2 < NT) ? tp + 2 : NT - 1; // clamp: harmless restage
    TILE4(1, tn2)
  }

#undef STAGE_HALF
#undef PHASE
#undef TILE4

#pragma unroll
  for (int f = 0; f < 8; ++f) {
    const int row0 = bm * 256 + wm * 128 + f * 16 + kg * 4;
#pragma unroll
    for (int j = 0; j < 4; ++j) {
      const int col = bn * 256 + wn * 64 + j * 16 + r15;
      float bv = 0.f;
      if constexpr (!SPLIT) bv = bias[(col < nbias) ? col : (nbias - 1)];
#pragma unroll
      for (int r = 0; r < 4; ++r)
        C[(size_t)(row0 + r) * ldc + col] = f2bf(acc[f][j][r] + bv);
    }
  }
}

// ---------- final output assembly; split-K reduce folded in ----------
// Exact r10 form (measured best). One t per block, high TLP; srcmap re-read
// is L2-resident; NT stores (327MB never re-read).
__global__ void fill_out(const int* __restrict__ srcmap,
                         const unsigned short* __restrict__ h2b,
                         const unsigned short* __restrict__ xpart,
                         const float* __restrict__ b3,
                         float* __restrict__ out) {
  int n4 = blockIdx.x * 256 + threadIdx.x;
  if (n4 >= N_VOX / 4) return;
  int t = blockIdx.y, b = blockIdx.z;
  size_t bt = (size_t)b * T_SZ + t;
  const int4 sm = ((const int4*)(srcmap + (size_t)b * N_VOX))[n4];
  const unsigned short* hrow = h2b + bt * KP;
  const unsigned short* xrow = xpart + bt * RP;
  const size_t zs = (size_t)BT_SZ * RP;
  auto val = [&](int s) -> float {
    if (s < 0) return 0.f;
    if (s < K_DIM) return bf2f(hrow[s]);
    int r = s - K_DIM;
    float acc = b3[r];
#pragma unroll
    for (int z = 0; z < SPLITK; ++z) acc += bf2f(xrow[z * zs + r]);
    return acc;
  };
  f32x4 v;
  v.x = val(sm.x); v.y = val(sm.y); v.z = val(sm.z); v.w = val(sm.w);
  __builtin_nontemporal_store(v, (f32x4*)(out + bt * N_VOX) + n4);
}

extern "C" void kernel_launch(void* const* d_in, const int* in_sizes, int n_in,
                              void* d_out, int out_size, void* d_ws, size_t ws_size,
                              hipStream_t stream) {
  const float* x          = (const float*)d_in[0];
  const int* bm           = (const int*)d_in[1];   // bool -> int32 per harness contract
  const int* index        = (const int*)d_in[2];
  const float* W1         = (const float*)d_in[3];
  const float* b1         = (const float*)d_in[4];
  const float* W2         = (const float*)d_in[5];
  const float* b2         = (const float*)d_in[6];
  const float* W3         = (const float*)d_in[7];
  const float* b3         = (const float*)d_in[8];
  float* out = (float*)d_out;

  char* ws = (char*)d_ws;
  size_t off = 0;
  auto alloc = [&](size_t bytes) -> void* {
    void* p = ws + off;
    off += (bytes + 255) & ~(size_t)255;
    return p;
  };
  unsigned short* xb    = (unsigned short*)alloc((size_t)BT_SZ * K1P * 2);
  unsigned short* w1t   = (unsigned short*)alloc((size_t)KP * K1P * 2);
  unsigned short* w2t   = (unsigned short*)alloc((size_t)KP * KP * 2);
  unsigned short* w3t   = (unsigned short*)alloc((size_t)RP * KP * 2);
  unsigned short* h1b   = (unsigned short*)alloc((size_t)BT_SZ * KP * 2);
  unsigned short* h2b   = (unsigned short*)alloc((size_t)BT_SZ * KP * 2);
  unsigned short* xpart = (unsigned short*)alloc((size_t)SPLITK * BT_SZ * RP * 2);
  unsigned char* cov = (unsigned char*)alloc((size_t)B_SZ * N_VOX);
  int* srcmap = (int*)alloc((size_t)B_SZ * N_VOX * 4);

  // fused prep: x-cvt, 3 weight transposes, coverage
  {
    int nblk = PREP_CVT + PREP_W1 + PREP_W2 + PREP_W3 + PREP_COV;
    prep_kernel<<<nblk, 256, 0, stream>>>(x, xb, W1, w1t, W2, w2t, W3, w3t, bm, cov);
  }
  map_kernel<<<B_SZ, 1024, 0, stream>>>(index, cov, srcmap);

  // GEMM chain
  {
    dim3 g(KP / 256, BT_SZ / 256);   // GEMM1 on 8-phase, K padded to 896
    gemm256<false><<<g, 512, 0, stream>>>(xb, w1t, b1, K_DIM, h1b,
                                          K1P, K1P, K1P, KP, 0);
  }
  {
    dim3 g(KP / 256, BT_SZ / 256);   // GEMM2
    gemm256<false><<<g, 512, 0, stream>>>(h1b, w2t, b2, K_DIM, h2b,
                                          KP, KP, KP, KP, 0);
  }
  {
    dim3 g(RP / 256, BT_SZ / 256, SPLITK);  // GEMM3: 8-phase split-K, 256 blocks
    gemm256<true><<<g, 512, 0, stream>>>(h2b, w3t, nullptr, 0, xpart,
                                         KP / SPLITK, KP, KP, RP,
                                         (size_t)BT_SZ * RP);
  }

  // output assembly (split-K reduce + bias folded in)
  {
    dim3 g((N_VOX / 4 + 255) / 256, T_SZ, B_SZ);
    fill_out<<<g, 256, 0, stream>>>(srcmap, h2b, xpart, b3, out);
  }
}